// Round 1
// baseline (445.205 us; speedup 1.0000x reference)
//
#include <hip/hip_runtime.h>

typedef __attribute__((ext_vector_type(8))) short bfrag;   // 8 x bf16 (4 VGPRs)
typedef __attribute__((ext_vector_type(4))) float ffrag;   // 4 x f32 accum

struct alignas(16) U8 { unsigned short v[8]; };

__device__ __forceinline__ unsigned short f2bf(float f) {
    unsigned int u = __float_as_uint(f);
    u += 0x7fffu + ((u >> 16) & 1u);   // round-to-nearest-even
    return (unsigned short)(u >> 16);
}

// ---- prep: transpose + bf16-convert weights into workspace ----
__global__ void prep_kernel(const float* __restrict__ Wlin,
                            const float* __restrict__ W1,
                            const float* __restrict__ W2,
                            unsigned short* __restrict__ wlinT,
                            unsigned short* __restrict__ w1T,
                            unsigned short* __restrict__ w2T) {
    int idx = blockIdx.x * 256 + threadIdx.x;           // 0..32767
    {   // W_lin [256][128] -> wlinT [128][256]
        int e = idx >> 7, h = idx & 127;
        wlinT[h * 256 + e] = f2bf(Wlin[idx]);
    }
    if (idx < 128 * 128) {  // W1/W2 [128][128] -> transposed
        int h = idx >> 7, f = idx & 127;
        w1T[f * 128 + h] = f2bf(W1[idx]);
        w2T[f * 128 + h] = f2bf(W2[idx]);
    }
}

// ---- fused per-node kernel: 1 block = 1 node (32 edges) ----
__global__ __launch_bounds__(256) void fused_kernel(
    const float* __restrict__ ef, const int* __restrict__ mask,
    const unsigned short* __restrict__ wlinT,
    const unsigned short* __restrict__ w1T,
    const unsigned short* __restrict__ w2T,
    const float* __restrict__ b_lin, const float* __restrict__ g_edge,
    const float* __restrict__ b_edge, const float* __restrict__ b1,
    const float* __restrict__ b2, const float* __restrict__ g_node,
    const float* __restrict__ b_node,
    float* __restrict__ out_node, float* __restrict__ out_edge) {

    __shared__ unsigned short s_ef[32 * 256];  // bf16, rows of 512B, XOR-swizzled
    __shared__ float          s_h[32 * 132];   // edge_hidden f32 (pad 132 to dodge conflicts)
    __shared__ unsigned short s_hn[32 * 128];  // h_norm bf16, rows of 256B, swizzled
    __shared__ unsigned short s_g[32 * 128];   // gelu out bf16, swizzled
    __shared__ float          s_red[256];      // [0..31]mu [32..63]rstd [64..95]mask [96..223]nodevals [224..225]

    const int tid = threadIdx.x;
    const int w = tid >> 6, lane = tid & 63, q = lane >> 4, c = lane & 15;
    const int n = blockIdx.x;
    const float* efn = ef + (size_t)n * (32 * 256);

    // 1. stage edge_features -> bf16 LDS (swizzled 16B slots)
    for (int i = 0; i < 4; ++i) {
        int s = i * 256 + tid;          // 16B-slot id, 1024 slots (32 rows x 32 slots)
        int row = s >> 5, cs = s & 31;
        const float4* p = (const float4*)(efn + (size_t)s * 8);
        float4 v0 = p[0], v1 = p[1];
        U8 u;
        u.v[0] = f2bf(v0.x); u.v[1] = f2bf(v0.y); u.v[2] = f2bf(v0.z); u.v[3] = f2bf(v0.w);
        u.v[4] = f2bf(v1.x); u.v[5] = f2bf(v1.y); u.v[6] = f2bf(v1.z); u.v[7] = f2bf(v1.w);
        int byte = row * 512 + ((cs * 16) ^ ((row & 7) << 4));
        *(U8*)((char*)s_ef + byte) = u;
    }
    __syncthreads();

    // 2. edge_hidden[32][128] = ef @ W_lin   (M=32, K=256, N=128)
    ffrag acc[2][2] = {};
    for (int kk = 0; kk < 8; ++kk) {
        bfrag a[2], b[2];
        for (int m = 0; m < 2; ++m) {
            int row = 16 * m + c;
            int byte = row * 512 + ((kk * 64 + q * 16) ^ ((row & 7) << 4));
            a[m] = *(const bfrag*)((const char*)s_ef + byte);
        }
        for (int j = 0; j < 2; ++j) {
            int col = 32 * w + 16 * j + c;
            b[j] = *(const bfrag*)(wlinT + col * 256 + kk * 32 + q * 8);
        }
        for (int m = 0; m < 2; ++m)
            for (int j = 0; j < 2; ++j)
                acc[m][j] = __builtin_amdgcn_mfma_f32_16x16x32_bf16(a[m], b[j], acc[m][j], 0, 0, 0);
    }
    for (int m = 0; m < 2; ++m)
        for (int j = 0; j < 2; ++j) {
            int col = 32 * w + 16 * j + c;
            float bl = b_lin[col];
            for (int r = 0; r < 4; ++r) {
                int row = 16 * m + 4 * q + r;
                s_h[row * 132 + col] = acc[m][j][r] + bl;
            }
        }
    __syncthreads();

    // 3. edge LayerNorm stats (8 threads per row)
    {
        int row = tid >> 3, jj = tid & 7;
        float s = 0.f, qs = 0.f;
        for (int i = 0; i < 16; ++i) {
            float x = s_h[row * 132 + jj * 16 + i];
            s += x; qs += x * x;
        }
        for (int d = 1; d < 8; d <<= 1) { s += __shfl_xor(s, d); qs += __shfl_xor(qs, d); }
        if (jj == 0) {
            float mu = s * (1.f / 128.f);
            float var = qs * (1.f / 128.f) - mu * mu;
            s_red[row] = mu;
            s_red[32 + row] = rsqrtf(var + 1e-5f);
        }
    }
    __syncthreads();

    // 4. h_norm -> bf16 LDS (swizzled)
    for (int i = 0; i < 2; ++i) {
        int s = i * 256 + tid;          // 512 slots (32 rows x 16 slots)
        int row = s >> 4, cs = s & 15;
        float mu = s_red[row], rstd = s_red[32 + row];
        U8 u;
        for (int p = 0; p < 8; ++p) {
            int col = cs * 8 + p;
            float x = (s_h[row * 132 + col] - mu) * rstd * g_edge[col] + b_edge[col];
            u.v[p] = f2bf(x);
        }
        int byte = row * 256 + ((cs * 16) ^ ((row & 7) << 4));
        *(U8*)((char*)s_hn + byte) = u;
    }
    __syncthreads();

    // 5. FFN layer 1 + gelu   (M=32, K=128, N=128)
    ffrag acc2[2][2] = {};
    for (int kk = 0; kk < 4; ++kk) {
        bfrag a[2], b[2];
        for (int m = 0; m < 2; ++m) {
            int row = 16 * m + c;
            int byte = row * 256 + ((kk * 64 + q * 16) ^ ((row & 7) << 4));
            a[m] = *(const bfrag*)((const char*)s_hn + byte);
        }
        for (int j = 0; j < 2; ++j) {
            int col = 32 * w + 16 * j + c;
            b[j] = *(const bfrag*)(w1T + col * 128 + kk * 32 + q * 8);
        }
        for (int m = 0; m < 2; ++m)
            for (int j = 0; j < 2; ++j)
                acc2[m][j] = __builtin_amdgcn_mfma_f32_16x16x32_bf16(a[m], b[j], acc2[m][j], 0, 0, 0);
    }
    for (int m = 0; m < 2; ++m)
        for (int j = 0; j < 2; ++j) {
            int col = 32 * w + 16 * j + c;
            float bb = b1[col];
            for (int r = 0; r < 4; ++r) {
                int row = 16 * m + 4 * q + r;
                float x = acc2[m][j][r] + bb;
                float t = tanhf(0.7978845608028654f * (x + 0.044715f * x * x * x));
                float ge = 0.5f * x * (1.f + t);
                int byte = row * 256 + ((col * 2) ^ ((row & 7) << 4));
                *(unsigned short*)((char*)s_g + byte) = f2bf(ge);
            }
        }
    __syncthreads();

    // 6. FFN layer 2 + residual -> edge_output (global + LDS for aggregation)
    ffrag acc3[2][2] = {};
    for (int kk = 0; kk < 4; ++kk) {
        bfrag a[2], b[2];
        for (int m = 0; m < 2; ++m) {
            int row = 16 * m + c;
            int byte = row * 256 + ((kk * 64 + q * 16) ^ ((row & 7) << 4));
            a[m] = *(const bfrag*)((const char*)s_g + byte);
        }
        for (int j = 0; j < 2; ++j) {
            int col = 32 * w + 16 * j + c;
            b[j] = *(const bfrag*)(w2T + col * 128 + kk * 32 + q * 8);
        }
        for (int m = 0; m < 2; ++m)
            for (int j = 0; j < 2; ++j)
                acc3[m][j] = __builtin_amdgcn_mfma_f32_16x16x32_bf16(a[m], b[j], acc3[m][j], 0, 0, 0);
    }
    float* eo_n = out_edge + (size_t)n * 4096;
    for (int m = 0; m < 2; ++m)
        for (int j = 0; j < 2; ++j) {
            int col = 32 * w + 16 * j + c;
            float bb = b2[col];
            for (int r = 0; r < 4; ++r) {
                int row = 16 * m + 4 * q + r;
                float v = acc3[m][j][r] + bb + s_h[row * 132 + col];
                eo_n[row * 128 + col] = v;
                s_h[row * 132 + col] = v;
            }
        }
    if (tid < 32) s_red[64 + tid] = (mask[n * 32 + tid] != 0) ? 1.f : 0.f;
    __syncthreads();

    // 7. masked aggregation over K=32 edges
    float nv = 0.f;
    if (tid < 128) {
        for (int k = 0; k < 32; ++k) nv += s_red[64 + k] * s_h[k * 132 + tid];
        s_red[96 + tid] = nv;
    }
    __syncthreads();

    // 8. node LayerNorm stats (wave 0)
    if (tid < 64) {
        float a = s_red[96 + tid], b = s_red[96 + 64 + tid];
        float s = a + b, qs = a * a + b * b;
        for (int d = 1; d < 64; d <<= 1) { s += __shfl_xor(s, d); qs += __shfl_xor(qs, d); }
        if (tid == 0) {
            float mu = s * (1.f / 128.f);
            float var = qs * (1.f / 128.f) - mu * mu;
            s_red[224] = mu;
            s_red[225] = rsqrtf(var + 1e-5f);
        }
    }
    __syncthreads();

    // 9. node output
    if (tid < 128) {
        float mu = s_red[224], rstd = s_red[225];
        out_node[(size_t)n * 128 + tid] = (nv - mu) * rstd * g_node[tid] + b_node[tid];
    }
}

extern "C" void kernel_launch(void* const* d_in, const int* in_sizes, int n_in,
                              void* d_out, int out_size, void* d_ws, size_t ws_size,
                              hipStream_t stream) {
    const float* ef     = (const float*)d_in[0];
    const int*   mask   = (const int*)d_in[1];
    const float* Wlin   = (const float*)d_in[2];
    const float* b_lin  = (const float*)d_in[3];
    const float* g_edge = (const float*)d_in[4];
    const float* b_edge = (const float*)d_in[5];
    const float* W1     = (const float*)d_in[6];
    const float* b1     = (const float*)d_in[7];
    const float* W2     = (const float*)d_in[8];
    const float* b2     = (const float*)d_in[9];
    const float* g_node = (const float*)d_in[10];
    const float* b_node = (const float*)d_in[11];

    int N = in_sizes[0] / (32 * 256);

    unsigned short* wlinT = (unsigned short*)d_ws;       // [128][256]
    unsigned short* w1T   = wlinT + 128 * 256;           // [128][128]
    unsigned short* w2T   = w1T + 128 * 128;             // [128][128]

    float* out_node = (float*)d_out;
    float* out_edge = out_node + (size_t)N * 128;

    prep_kernel<<<128, 256, 0, stream>>>(Wlin, W1, W2, wlinT, w1T, w2T);
    fused_kernel<<<N, 256, 0, stream>>>(ef, mask, wlinT, w1T, w2T,
                                        b_lin, g_edge, b_edge, b1, b2,
                                        g_node, b_node, out_node, out_edge);
}

// Round 2
// 385.914 us; speedup vs baseline: 1.1536x; 1.1536x over previous
//
#include <hip/hip_runtime.h>

typedef __attribute__((ext_vector_type(8))) short bfrag;   // 8 x bf16 (4 VGPRs)
typedef __attribute__((ext_vector_type(4))) float ffrag;   // 4 x f32 accum

struct alignas(16) U8v { unsigned int u[4]; };

__device__ __forceinline__ unsigned int cvt_pk_bf16(float lo, float hi) {
    unsigned int r;
    asm("v_cvt_pk_bf16_f32 %0, %1, %2" : "=v"(r) : "v"(lo), "v"(hi));
    return r;
}
__device__ __forceinline__ unsigned short f2bf1(float x) {
    return (unsigned short)cvt_pk_bf16(x, x);
}

// ---- prep: transpose + bf16-convert weights into workspace ----
__global__ void prep_kernel(const float* __restrict__ Wlin,
                            const float* __restrict__ W1,
                            const float* __restrict__ W2,
                            unsigned short* __restrict__ wlinT,
                            unsigned short* __restrict__ w1T,
                            unsigned short* __restrict__ w2T) {
    int idx = blockIdx.x * 256 + threadIdx.x;           // 0..32767
    {   // W_lin [256][128] -> wlinT [128][256]
        int e = idx >> 7, h = idx & 127;
        wlinT[h * 256 + e] = f2bf1(Wlin[idx]);
    }
    if (idx < 128 * 128) {  // W1/W2 [128][128] -> transposed
        int h = idx >> 7, f = idx & 127;
        w1T[f * 128 + h] = f2bf1(W1[idx]);
        w2T[f * 128 + h] = f2bf1(W2[idx]);
    }
}

// ---- fused per-node kernel: 1 block = 1 node (32 edges) ----
// LDS ~18.4KB; edge_hidden lives in registers; LN/aggregation via shfl.
__global__ __launch_bounds__(256, 4) void fused_kernel(
    const float* __restrict__ ef, const int* __restrict__ mask,
    const unsigned short* __restrict__ wlinT,
    const unsigned short* __restrict__ w1T,
    const unsigned short* __restrict__ w2T,
    const float* __restrict__ b_lin, const float* __restrict__ g_edge,
    const float* __restrict__ b_edge, const float* __restrict__ b1,
    const float* __restrict__ b2, const float* __restrict__ g_node,
    const float* __restrict__ b_node,
    float* __restrict__ out_node, float* __restrict__ out_edge) {

    __shared__ char  smem[16384];   // phase1-2: ef bf16 [32 rows x 512B, swz]
                                    // phase4+: [0:8K)=h_norm bf16 [32x256B, swz], [8K:16K)=gelu
    __shared__ float s_part[256];   // per-wave LN partials: w*64 + row*2 + {sum,sq}
    __shared__ float s_red[256];    // [0:32)mu [32:64)rstd [64:96)maskf [96:224)node vals [224]mu [225]rstd

    const int tid = threadIdx.x;
    const int w = tid >> 6, lane = tid & 63, q = lane >> 4, c = lane & 15;
    const int n = blockIdx.x;
    const float* efn = ef + (size_t)n * 8192;

    if (tid < 32) s_red[64 + tid] = (mask[n * 32 + tid] != 0) ? 1.f : 0.f;

    // ---- phase 1: stage edge_features -> bf16 LDS (swizzled 16B slots) ----
    #pragma unroll
    for (int i = 0; i < 4; ++i) {
        int s = i * 256 + tid;          // 16B-slot id, 1024 slots (32 rows x 32 slots)
        int row = s >> 5, cs = s & 31;
        const float4* p = (const float4*)(efn + (size_t)s * 8);
        float4 v0 = p[0], v1 = p[1];
        U8v u;
        u.u[0] = cvt_pk_bf16(v0.x, v0.y); u.u[1] = cvt_pk_bf16(v0.z, v0.w);
        u.u[2] = cvt_pk_bf16(v1.x, v1.y); u.u[3] = cvt_pk_bf16(v1.z, v1.w);
        *(U8v*)(smem + row * 512 + ((cs * 16) ^ ((row & 7) << 4))) = u;
    }
    __syncthreads();

    // ---- phase 2: edge_hidden = ef @ W_lin  (M=32,K=256,N=128), kept in regs ----
    ffrag acc[2][2] = {};
    #pragma unroll
    for (int kk = 0; kk < 8; ++kk) {
        bfrag a[2], b[2];
        #pragma unroll
        for (int m = 0; m < 2; ++m) {
            int row = 16 * m + c;
            a[m] = *(const bfrag*)(smem + row * 512 + ((kk * 64 + q * 16) ^ ((row & 7) << 4)));
        }
        #pragma unroll
        for (int j = 0; j < 2; ++j) {
            int col = 32 * w + 16 * j + c;
            b[j] = *(const bfrag*)(wlinT + col * 256 + kk * 32 + q * 8);
        }
        #pragma unroll
        for (int m = 0; m < 2; ++m)
            #pragma unroll
            for (int j = 0; j < 2; ++j)
                acc[m][j] = __builtin_amdgcn_mfma_f32_16x16x32_bf16(a[m], b[j], acc[m][j], 0, 0, 0);
    }
    float h[2][2][4];
    #pragma unroll
    for (int j = 0; j < 2; ++j) {
        float bl = b_lin[32 * w + 16 * j + c];
        #pragma unroll
        for (int m = 0; m < 2; ++m)
            #pragma unroll
            for (int r = 0; r < 4; ++r)
                h[m][j][r] = acc[m][j][r] + bl;
    }

    // ---- edge-LN stats: in-wave reduce over c (16 lanes), cross-wave via LDS ----
    #pragma unroll
    for (int m = 0; m < 2; ++m)
        #pragma unroll
        for (int r = 0; r < 4; ++r) {
            float s  = h[m][0][r] + h[m][1][r];
            float qv = h[m][0][r] * h[m][0][r] + h[m][1][r] * h[m][1][r];
            #pragma unroll
            for (int d = 1; d < 16; d <<= 1) { s += __shfl_xor(s, d); qv += __shfl_xor(qv, d); }
            if (c == 0) {
                int row = 16 * m + 4 * q + r;
                s_part[w * 64 + row * 2]     = s;
                s_part[w * 64 + row * 2 + 1] = qv;
            }
        }
    __syncthreads();
    if (tid < 32) {
        float s = 0.f, qv = 0.f;
        #pragma unroll
        for (int ww = 0; ww < 4; ++ww) { s += s_part[ww * 64 + tid * 2]; qv += s_part[ww * 64 + tid * 2 + 1]; }
        float mu = s * (1.f / 128.f);
        float var = qv * (1.f / 128.f) - mu * mu;
        s_red[tid] = mu;
        s_red[32 + tid] = rsqrtf(var + 1e-5f);
    }
    __syncthreads();

    // ---- phase 4: normalize from regs -> bf16 h_norm in LDS (scattered b16, swz) ----
    float gc[2], bc[2];
    #pragma unroll
    for (int j = 0; j < 2; ++j) {
        int col = 32 * w + 16 * j + c;
        gc[j] = g_edge[col]; bc[j] = b_edge[col];
    }
    #pragma unroll
    for (int m = 0; m < 2; ++m)
        #pragma unroll
        for (int r = 0; r < 4; ++r) {
            int row = 16 * m + 4 * q + r;
            float mu = s_red[row], rs = s_red[32 + row];
            #pragma unroll
            for (int j = 0; j < 2; ++j) {
                int col = 32 * w + 16 * j + c;
                float x = (h[m][j][r] - mu) * rs * gc[j] + bc[j];
                *(unsigned short*)(smem + row * 256 + ((col * 2) ^ ((row & 7) << 4))) = f2bf1(x);
            }
        }
    __syncthreads();

    // ---- phase 5: FFN1 + gelu (M=32,K=128,N=128) ----
    ffrag acc2[2][2] = {};
    #pragma unroll
    for (int kk = 0; kk < 4; ++kk) {
        bfrag a[2], b[2];
        #pragma unroll
        for (int m = 0; m < 2; ++m) {
            int row = 16 * m + c;
            a[m] = *(const bfrag*)(smem + row * 256 + ((kk * 64 + q * 16) ^ ((row & 7) << 4)));
        }
        #pragma unroll
        for (int j = 0; j < 2; ++j) {
            int col = 32 * w + 16 * j + c;
            b[j] = *(const bfrag*)(w1T + col * 128 + kk * 32 + q * 8);
        }
        #pragma unroll
        for (int m = 0; m < 2; ++m)
            #pragma unroll
            for (int j = 0; j < 2; ++j)
                acc2[m][j] = __builtin_amdgcn_mfma_f32_16x16x32_bf16(a[m], b[j], acc2[m][j], 0, 0, 0);
    }
    {
        float b1c[2];
        #pragma unroll
        for (int j = 0; j < 2; ++j) b1c[j] = b1[32 * w + 16 * j + c];
        #pragma unroll
        for (int m = 0; m < 2; ++m)
            #pragma unroll
            for (int j = 0; j < 2; ++j) {
                int col = 32 * w + 16 * j + c;
                #pragma unroll
                for (int r = 0; r < 4; ++r) {
                    int row = 16 * m + 4 * q + r;
                    float x = acc2[m][j][r] + b1c[j];
                    // gelu(tanh approx) = x * sigmoid(2*0.79788456*(x+0.044715x^3))
                    float y = 0.7978845608028654f * x * (1.f + 0.044715f * x * x);
                    float e;
                    asm("v_exp_f32 %0, %1" : "=v"(e) : "v"(-2.885390081777927f * y)); // 2^(-2y*log2e)
                    float rcp;
                    asm("v_rcp_f32 %0, %1" : "=v"(rcp) : "v"(1.f + e));
                    float ge = x * rcp;
                    *(unsigned short*)(smem + 8192 + row * 256 + ((col * 2) ^ ((row & 7) << 4))) = f2bf1(ge);
                }
            }
    }
    __syncthreads();

    // ---- phase 6: FFN2 + residual -> edge_output; masked row-agg in regs ----
    ffrag acc3[2][2] = {};
    #pragma unroll
    for (int kk = 0; kk < 4; ++kk) {
        bfrag a[2], b[2];
        #pragma unroll
        for (int m = 0; m < 2; ++m) {
            int row = 16 * m + c;
            a[m] = *(const bfrag*)(smem + 8192 + row * 256 + ((kk * 64 + q * 16) ^ ((row & 7) << 4)));
        }
        #pragma unroll
        for (int j = 0; j < 2; ++j) {
            int col = 32 * w + 16 * j + c;
            b[j] = *(const bfrag*)(w2T + col * 128 + kk * 32 + q * 8);
        }
        #pragma unroll
        for (int m = 0; m < 2; ++m)
            #pragma unroll
            for (int j = 0; j < 2; ++j)
                acc3[m][j] = __builtin_amdgcn_mfma_f32_16x16x32_bf16(a[m], b[j], acc3[m][j], 0, 0, 0);
    }
    float* eo_n = out_edge + (size_t)n * 4096;
    float np0 = 0.f, np1 = 0.f;
    {
        float b2c[2];
        #pragma unroll
        for (int j = 0; j < 2; ++j) b2c[j] = b2[32 * w + 16 * j + c];
        #pragma unroll
        for (int m = 0; m < 2; ++m)
            #pragma unroll
            for (int r = 0; r < 4; ++r) {
                int row = 16 * m + 4 * q + r;
                float mv = s_red[64 + row];
                {
                    int col = 32 * w + c;
                    float v = acc3[m][0][r] + b2c[0] + h[m][0][r];
                    eo_n[row * 128 + col] = v;
                    np0 += mv * v;
                }
                {
                    int col = 32 * w + 16 + c;
                    float v = acc3[m][1][r] + b2c[1] + h[m][1][r];
                    eo_n[row * 128 + col] = v;
                    np1 += mv * v;
                }
            }
    }
    np0 += __shfl_xor(np0, 16); np0 += __shfl_xor(np0, 32);
    np1 += __shfl_xor(np1, 16); np1 += __shfl_xor(np1, 32);
    if (q == 0) {
        s_red[96 + 32 * w + c]      = np0;
        s_red[96 + 32 * w + 16 + c] = np1;
    }
    __syncthreads();

    // ---- phase 7: node LN ----
    if (tid < 64) {
        float v0 = s_red[96 + tid], v1 = s_red[160 + tid];
        float s = v0 + v1, qv = v0 * v0 + v1 * v1;
        #pragma unroll
        for (int d = 1; d < 64; d <<= 1) { s += __shfl_xor(s, d); qv += __shfl_xor(qv, d); }
        if (tid == 0) {
            float mu = s * (1.f / 128.f);
            float var = qv * (1.f / 128.f) - mu * mu;
            s_red[224] = mu;
            s_red[225] = rsqrtf(var + 1e-5f);
        }
    }
    __syncthreads();
    if (tid < 128) {
        float nv = s_red[96 + tid];
        out_node[(size_t)n * 128 + tid] = (nv - s_red[224]) * s_red[225] * g_node[tid] + b_node[tid];
    }
}

extern "C" void kernel_launch(void* const* d_in, const int* in_sizes, int n_in,
                              void* d_out, int out_size, void* d_ws, size_t ws_size,
                              hipStream_t stream) {
    const float* ef     = (const float*)d_in[0];
    const int*   mask   = (const int*)d_in[1];
    const float* Wlin   = (const float*)d_in[2];
    const float* b_lin  = (const float*)d_in[3];
    const float* g_edge = (const float*)d_in[4];
    const float* b_edge = (const float*)d_in[5];
    const float* W1     = (const float*)d_in[6];
    const float* b1     = (const float*)d_in[7];
    const float* W2     = (const float*)d_in[8];
    const float* b2     = (const float*)d_in[9];
    const float* g_node = (const float*)d_in[10];
    const float* b_node = (const float*)d_in[11];

    int N = in_sizes[0] / (32 * 256);

    unsigned short* wlinT = (unsigned short*)d_ws;       // [128][256]
    unsigned short* w1T   = wlinT + 128 * 256;           // [128][128]
    unsigned short* w2T   = w1T + 128 * 128;             // [128][128]

    float* out_node = (float*)d_out;
    float* out_edge = out_node + (size_t)N * 128;

    prep_kernel<<<128, 256, 0, stream>>>(Wlin, W1, W2, wlinT, w1T, w2T);
    fused_kernel<<<N, 256, 0, stream>>>(ef, mask, wlinT, w1T, w2T,
                                        b_lin, g_edge, b_edge, b1, b2,
                                        g_node, b_node, out_node, out_edge);
}